// Round 3
// baseline (925.209 us; speedup 1.0000x reference)
//
#include <hip/hip_runtime.h>

typedef unsigned short u16;
typedef unsigned int   u32;

#define NB     512
#define INC    256
#define NHEADS 8
#define HW     361
#define NPIX   184832      /* NB*HW */
#define NTOT   768
#define NWG_M  1444        /* NPIX/128 */
#define EPSBN  1e-5f

typedef __bf16 bf16x8 __attribute__((ext_vector_type(8)));
typedef float  f32x4  __attribute__((ext_vector_type(4)));

__device__ __forceinline__ u16 f2bf(float f) {
  u32 u = __float_as_uint(f);
  u += 0x7fffu + ((u >> 16) & 1u);          // round-to-nearest-even
  return (u16)(u >> 16);
}
__device__ __forceinline__ float bf2f(u16 v) {
  return __uint_as_float(((u32)v) << 16);
}

// ---------------- kernel 0: W -> bf16 [768][256] plain rows, bias, zero stats
__global__ __launch_bounds__(256) void k_prep(
    const float* __restrict__ Wq, const float* __restrict__ bq,
    const float* __restrict__ Wk, const float* __restrict__ bk,
    const float* __restrict__ Wv, const float* __restrict__ bv,
    u16* __restrict__ Wall, float* __restrict__ ball, float* __restrict__ stats) {
  const int n = blockIdx.x, t = threadIdx.x;
  const float* src; const float* bs; int r;
  if (n < 256)      { src = Wq; bs = bq; r = n; }
  else if (n < 512) { src = Wk; bs = bk; r = n - 256; }
  else              { src = Wv; bs = bv; r = n - 512; }
  Wall[n * 256 + t] = f2bf(src[r * 256 + t]);
  if (t == 0) ball[n] = bs[r];
  if (n == 0) { for (int i = t; i < 1536; i += 256) stats[i] = 0.f; }
}

// ---------------- kernel 0b: x [B][256][361] f32 -> xT [NPIX][256] bf16, ROTATED columns
// logical 16B column k16 stored at physical slot (k16 + 4*(m&7)) & 31
__global__ __launch_bounds__(384) void k_xt(const float* __restrict__ x, u16* __restrict__ xT) {
  const int bb = blockIdx.x, t = threadIdx.x;
  if (t >= HW) return;
  const size_t m = (size_t)bb * HW + t;
  const float* xp = x + (size_t)bb * INC * HW + t;
  char* dst = (char*)xT + m * 512;
  const int rot = ((int)m & 7) * 4;
  #pragma unroll 1
  for (int cc = 0; cc < INC; cc += 32) {
    __align__(16) u16 tmp[32];
    #pragma unroll
    for (int c = 0; c < 32; ++c) tmp[c] = f2bf(xp[(size_t)(cc + c) * HW]);
    #pragma unroll
    for (int p = 0; p < 4; ++p) {
      int slot = ((cc >> 3) + p + rot) & 31;
      *(uint4*)(dst + slot * 16) = ((const uint4*)tmp)[p];
    }
  }
}

// ---------------- kernel 1: QKV GEMM, swapped operands, vector-store epilogue
// outputs all in [bh][px][32c] layout
__global__ __launch_bounds__(512, 4) void k_gemm(
    const u16* __restrict__ xT, const u16* __restrict__ Wall,
    const float* __restrict__ ball,
    u16* __restrict__ qQ, u16* __restrict__ qK, u16* __restrict__ qV,
    float* __restrict__ stats) {
  __shared__ u16   Al[128 * 256];                  // 64 KB, rotated rows
  __shared__ float bl[NTOT];
  const int tid = threadIdx.x;
  const int m0  = blockIdx.x * 128;
  {
    const uint4* src = (const uint4*)(xT + (size_t)m0 * 256);
    uint4* dst = (uint4*)Al;
    #pragma unroll
    for (int i = tid; i < 4096; i += 512) dst[i] = src[i];
  }
  for (int i = tid; i < NTOT; i += 512) bl[i] = ball[i];
  __syncthreads();

  const int lane = tid & 63, w = tid >> 6;
  const int wM = w & 1, wN = w >> 1;               // 2 M-halves x 4 N-quarters
  const int l15 = lane & 15, kq = lane >> 4;

  // per-thread output row bases (global store): bb*92416 + px*32
  int obase[4];
  #pragma unroll
  for (int mi = 0; mi < 4; ++mi) {
    int pg = m0 + wM * 64 + mi * 16 + l15;
    int bb = pg / 361, px = pg - bb * 361;
    obase[mi] = bb * 92416 + px * 32;
  }
  int rowb[4];
  #pragma unroll
  for (int mi = 0; mi < 4; ++mi) rowb[mi] = (wM * 64 + mi * 16 + l15) * 512;
  const int col0 = kq * 16 + (l15 & 7) * 64;       // rotated col for ks=0
  const char* Alb = (const char*)Al;

  #pragma unroll 1
  for (int nt = 0; nt < 3; ++nt) {
    f32x4 acc[4][4];
    #pragma unroll
    for (int i = 0; i < 4; ++i)
      #pragma unroll
      for (int j = 0; j < 4; ++j) acc[i][j] = (f32x4){0.f, 0.f, 0.f, 0.f};

    const int nb = nt * 256 + wN * 64;
    const char* wrow[4];
    #pragma unroll
    for (int ni = 0; ni < 4; ++ni)
      wrow[ni] = (const char*)Wall + (size_t)(nb + ni * 16 + l15) * 512 + kq * 16;

    int col = col0;
    #pragma unroll
    for (int ks = 0; ks < 8; ++ks) {
      bf16x8 a[4], b[4];
      #pragma unroll
      for (int ni = 0; ni < 4; ++ni)
        a[ni] = __builtin_bit_cast(bf16x8, *(const uint4*)(wrow[ni] + ks * 64));
      #pragma unroll
      for (int mi = 0; mi < 4; ++mi)
        b[mi] = __builtin_bit_cast(bf16x8, *(const uint4*)(Alb + rowb[mi] + col));
      col = (col + 64) & 511;
      #pragma unroll
      for (int mi = 0; mi < 4; ++mi)
        #pragma unroll
        for (int ni = 0; ni < 4; ++ni)
          acc[mi][ni] = __builtin_amdgcn_mfma_f32_16x16x32_bf16(a[ni], b[mi], acc[mi][ni], 0, 0, 0);
    }

    u16* qp = (nt == 0) ? qQ : (nt == 1) ? qK : qV;
    #pragma unroll
    for (int ni = 0; ni < 4; ++ni) {
      const int ch0 = wN * 64 + ni * 16 + kq * 4;          // 0..255 (quad-aligned)
      const int hof = (ch0 >> 5) * 11552 + (ch0 & 31);     // h*32*361 + c
      const float b0 = bl[nt * 256 + ch0 + 0];
      const float b1 = bl[nt * 256 + ch0 + 1];
      const float b2 = bl[nt * 256 + ch0 + 2];
      const float b3 = bl[nt * 256 + ch0 + 3];
      float s0 = 0.f, s1 = 0.f, s2 = 0.f, s3 = 0.f;
      float q0 = 0.f, q1 = 0.f, q2 = 0.f, q3 = 0.f;
      #pragma unroll
      for (int mi = 0; mi < 4; ++mi) {
        float v0 = acc[mi][ni][0] + b0;
        float v1 = acc[mi][ni][1] + b1;
        float v2 = acc[mi][ni][2] + b2;
        float v3 = acc[mi][ni][3] + b3;
        u32 lo = (u32)f2bf(v0) | ((u32)f2bf(v1) << 16);
        u32 hi = (u32)f2bf(v2) | ((u32)f2bf(v3) << 16);
        *(uint2*)(qp + obase[mi] + hof) = make_uint2(lo, hi);
        s0 += v0; s1 += v1; s2 += v2; s3 += v3;
        q0 += v0 * v0; q1 += v1 * v1; q2 += v2 * v2; q3 += v3 * v3;
      }
      #pragma unroll
      for (int st = 1; st < 16; st <<= 1) {
        s0 += __shfl_xor(s0, st); s1 += __shfl_xor(s1, st);
        s2 += __shfl_xor(s2, st); s3 += __shfl_xor(s3, st);
        q0 += __shfl_xor(q0, st); q1 += __shfl_xor(q1, st);
        q2 += __shfl_xor(q2, st); q3 += __shfl_xor(q3, st);
      }
      if (l15 == 0) {
        const int g = nt * 256 + ch0;
        atomicAdd(&stats[g + 0], s0); atomicAdd(&stats[NTOT + g + 0], q0);
        atomicAdd(&stats[g + 1], s1); atomicAdd(&stats[NTOT + g + 1], q1);
        atomicAdd(&stats[g + 2], s2); atomicAdd(&stats[NTOT + g + 2], q2);
        atomicAdd(&stats[g + 3], s3); atomicAdd(&stats[NTOT + g + 3], q3);
      }
    }
  }
}

// ---------------- kernel 2: finalize BN -> s_all, t_all
__global__ void k_stats(const float* __restrict__ stats,
                        const float* __restrict__ gQ, const float* __restrict__ betaQ,
                        const float* __restrict__ gK, const float* __restrict__ betaK,
                        const float* __restrict__ gV, const float* __restrict__ betaV,
                        float* __restrict__ s_all, float* __restrict__ t_all) {
  const int n = threadIdx.x;
  if (n >= NTOT) return;
  const float invP = 1.f / (float)NPIX;
  float mean = stats[n] * invP;
  float var  = stats[NTOT + n] * invP - mean * mean;
  float g, be;
  if (n < 256)      { g = gQ[n];       be = betaQ[n]; }
  else if (n < 512) { g = gK[n - 256]; be = betaK[n - 256]; }
  else              { g = gV[n - 512]; be = betaV[n - 512]; }
  float s = g * rsqrtf(var + EPSBN);
  s_all[n] = s;
  t_all[n] = be - s * mean;
}

// ---------------- kernel 3: neighbor attention + softmax + ReLU + residual
// one block per (bb,h); K then V phase-share one 23KB LDS buffer (transposed on stage)
__global__ __launch_bounds__(384, 6) void k_attn(
    const u16* __restrict__ qQ, const u16* __restrict__ qK, const u16* __restrict__ qV,
    const float* __restrict__ s_all, const float* __restrict__ t_all,
    const float* __restrict__ x, float* __restrict__ out) {
  __shared__ __align__(16) u16 KV[32 * HW];          // [c][px]
  __shared__ float sQ[32], tQ[32], sK[32], tK[32], sV[32], tV[32];
  const int bb = blockIdx.x, h = blockIdx.y, tid = threadIdx.x;
  const int bh = bb * NHEADS + h;

  if (tid < 96) {
    int which = tid >> 5, c = tid & 31;
    float sv = s_all[which * 256 + h * 32 + c];
    float tv = t_all[which * 256 + h * 32 + c];
    if (which == 0)      { sQ[c] = sv; tQ[c] = tv; }
    else if (which == 1) { sK[c] = sv; tK[c] = tv; }
    else                 { sV[c] = sv; tV[c] = tv; }
  }
  // stage K: contiguous read [px][c], transpose into LDS [c][px]
  {
    const uint4* gk = (const uint4*)(qK + (size_t)bh * 11552);
    for (int i = tid; i < 1444; i += 384) {
      uint4 kk = gk[i];
      int px = i >> 2, c0 = (i & 3) << 3;
      u16* d = KV + c0 * HW + px;
      d[0 * HW] = (u16)(kk.x & 0xffffu); d[1 * HW] = (u16)(kk.x >> 16);
      d[2 * HW] = (u16)(kk.y & 0xffffu); d[3 * HW] = (u16)(kk.y >> 16);
      d[4 * HW] = (u16)(kk.z & 0xffffu); d[5 * HW] = (u16)(kk.z >> 16);
      d[6 * HW] = (u16)(kk.w & 0xffffu); d[7 * HW] = (u16)(kk.w >> 16);
    }
  }
  __syncthreads();

  const int px = tid;
  const bool act = tid < HW;
  float a0 = 0.f, a1 = 0.f, a2 = 0.f, a3 = 0.f;
  int pn0 = 0, pn1 = 0, pn2 = 0, pn3 = 0;
  if (act) {
    const int yy = px / 19, xx = px - yy * 19;
    const bool i0 = yy > 0, i1 = yy < 18, i2 = xx > 0, i3 = xx < 18;
    pn0 = i0 ? px - 19 : px;  pn1 = i1 ? px + 19 : px;
    pn2 = i2 ? px - 1  : px;  pn3 = i3 ? px + 1  : px;
    const u16* K0 = KV + pn0; const u16* K1 = KV + pn1;
    const u16* K2 = KV + pn2; const u16* K3 = KV + pn3;
    const uint4* q4 = (const uint4*)(qQ + ((size_t)bh * HW + px) * 32);
    uint4 qA = q4[0], qB = q4[1], qC = q4[2], qD = q4[3];
    float d0 = 0.f, d1 = 0.f, d2 = 0.f, d3 = 0.f, Ct = 0.f;
#define CH2(wrd, c0) { \
    float ql = bf2f((u16)((wrd) & 0xffffu)), qh = bf2f((u16)((wrd) >> 16)); \
    float qn0 = sQ[c0] * ql + tQ[c0]; \
    float qn1 = sQ[(c0)+1] * qh + tQ[(c0)+1]; \
    Ct += qn0 * tK[c0] + qn1 * tK[(c0)+1]; \
    float w0 = qn0 * sK[c0], w1 = qn1 * sK[(c0)+1]; \
    d0 += w0 * bf2f(K0[(c0)*HW]) + w1 * bf2f(K0[((c0)+1)*HW]); \
    d1 += w0 * bf2f(K1[(c0)*HW]) + w1 * bf2f(K1[((c0)+1)*HW]); \
    d2 += w0 * bf2f(K2[(c0)*HW]) + w1 * bf2f(K2[((c0)+1)*HW]); \
    d3 += w0 * bf2f(K3[(c0)*HW]) + w1 * bf2f(K3[((c0)+1)*HW]); \
  }
    CH2(qA.x, 0)  CH2(qA.y, 2)  CH2(qA.z, 4)  CH2(qA.w, 6)
    CH2(qB.x, 8)  CH2(qB.y, 10) CH2(qB.z, 12) CH2(qB.w, 14)
    CH2(qC.x, 16) CH2(qC.y, 18) CH2(qC.z, 20) CH2(qC.w, 22)
    CH2(qD.x, 24) CH2(qD.y, 26) CH2(qD.z, 28) CH2(qD.w, 30)
#undef CH2
    const float rs = 0.17677669529663687f;     // 1/sqrt(32)
    float l0 = i0 ? (d0 + Ct) * rs : 0.f;
    float l1 = i1 ? (d1 + Ct) * rs : 0.f;
    float l2 = i2 ? (d2 + Ct) * rs : 0.f;
    float l3 = i3 ? (d3 + Ct) * rs : 0.f;
    float mx = fmaxf(fmaxf(l0, l1), fmaxf(l2, l3));
    float e0 = __expf(l0 - mx), e1 = __expf(l1 - mx);
    float e2 = __expf(l2 - mx), e3 = __expf(l3 - mx);
    float inv = 1.f / (e0 + e1 + e2 + e3);
    a0 = i0 ? e0 * inv : 0.f;  a1 = i1 ? e1 * inv : 0.f;
    a2 = i2 ? e2 * inv : 0.f;  a3 = i3 ? e3 * inv : 0.f;
  }
  __syncthreads();
  // stage V over the same buffer (transposed)
  {
    const uint4* gv = (const uint4*)(qV + (size_t)bh * 11552);
    for (int i = tid; i < 1444; i += 384) {
      uint4 vv = gv[i];
      int pxs = i >> 2, c0 = (i & 3) << 3;
      u16* d = KV + c0 * HW + pxs;
      d[0 * HW] = (u16)(vv.x & 0xffffu); d[1 * HW] = (u16)(vv.x >> 16);
      d[2 * HW] = (u16)(vv.y & 0xffffu); d[3 * HW] = (u16)(vv.y >> 16);
      d[4 * HW] = (u16)(vv.z & 0xffffu); d[5 * HW] = (u16)(vv.z >> 16);
      d[6 * HW] = (u16)(vv.w & 0xffffu); d[7 * HW] = (u16)(vv.w >> 16);
    }
  }
  __syncthreads();

  if (act) {
    const float ai = a0 + a1 + a2 + a3;
    const u16* V0 = KV + pn0; const u16* V1 = KV + pn1;
    const u16* V2 = KV + pn2; const u16* V3 = KV + pn3;
    const size_t gb = ((size_t)bb * 256 + h * 32) * HW + px;
    #pragma unroll
    for (int oc = 0; oc < 32; ++oc) {
      float v = a0 * bf2f(V0[oc * HW]) + a1 * bf2f(V1[oc * HW])
              + a2 * bf2f(V2[oc * HW]) + a3 * bf2f(V3[oc * HW]);
      float o = sV[oc] * v + tV[oc] * ai;
      o = fmaxf(o, 0.f);
      const size_t g = gb + (size_t)oc * HW;
      out[g] = o + x[g];
    }
  }
}

// ---------------- workspace layout
constexpr size_t OFF_XT    = 0;
constexpr size_t SZ_XT     = (size_t)NPIX * 512;
constexpr size_t OFF_WALL  = OFF_XT + SZ_XT;
constexpr size_t SZ_WALL   = (size_t)NTOT * 512;
constexpr size_t OFF_BALL  = OFF_WALL + SZ_WALL;
constexpr size_t OFF_STATS = OFF_BALL + NTOT * 4;
constexpr size_t OFF_SALL  = OFF_STATS + 2 * NTOT * 4;
constexpr size_t OFF_TALL  = OFF_SALL + NTOT * 4;
constexpr size_t OFF_QQ    = OFF_TALL + NTOT * 4;
constexpr size_t SZ_ONE    = (size_t)NPIX * 256 * 2;
constexpr size_t OFF_QK    = OFF_QQ + SZ_ONE;
constexpr size_t OFF_QV    = OFF_QK + SZ_ONE;
constexpr size_t WS_NEEDED = OFF_QV + SZ_ONE;

extern "C" void kernel_launch(void* const* d_in, const int* in_sizes, int n_in,
                              void* d_out, int out_size, void* d_ws, size_t ws_size,
                              hipStream_t stream) {
  (void)in_sizes; (void)n_in; (void)out_size;
  if (ws_size < WS_NEEDED) return;

  const float* x     = (const float*)d_in[0];
  const float* Wq    = (const float*)d_in[1];
  const float* bq    = (const float*)d_in[2];
  const float* Wk    = (const float*)d_in[3];
  const float* bk    = (const float*)d_in[4];
  const float* Wv    = (const float*)d_in[5];
  const float* bv    = (const float*)d_in[6];
  const float* gQ    = (const float*)d_in[7];
  const float* betaQ = (const float*)d_in[8];
  const float* gK    = (const float*)d_in[9];
  const float* betaK = (const float*)d_in[10];
  const float* gV    = (const float*)d_in[11];
  const float* betaV = (const float*)d_in[12];
  float* out = (float*)d_out;

  char* w = (char*)d_ws;
  u16*   xT    = (u16*)(w + OFF_XT);
  u16*   Wall  = (u16*)(w + OFF_WALL);
  float* ball  = (float*)(w + OFF_BALL);
  float* stats = (float*)(w + OFF_STATS);
  float* s_all = (float*)(w + OFF_SALL);
  float* t_all = (float*)(w + OFF_TALL);
  u16*   qQ    = (u16*)(w + OFF_QQ);
  u16*   qK    = (u16*)(w + OFF_QK);
  u16*   qV    = (u16*)(w + OFF_QV);

  k_prep<<<NTOT, 256, 0, stream>>>(Wq, bq, Wk, bk, Wv, bv, Wall, ball, stats);
  k_xt<<<NB, 384, 0, stream>>>(x, xT);
  k_gemm<<<NWG_M, 512, 0, stream>>>(xT, Wall, ball, qQ, qK, qV, stats);
  k_stats<<<1, NTOT, 0, stream>>>(stats, gQ, betaQ, gK, betaK, gV, betaV, s_all, t_all);
  k_attn<<<dim3(NB, NHEADS), 384, 0, stream>>>(qQ, qK, qV, s_all, t_all, x, out);
}

// Round 4
// 706.752 us; speedup vs baseline: 1.3091x; 1.3091x over previous
//
#include <hip/hip_runtime.h>

typedef unsigned short u16;
typedef unsigned int   u32;

#define NB     512
#define INC    256
#define NHEADS 8
#define HW     361
#define NPIX   184832      /* NB*HW */
#define NTOT   768
#define NWG_M  1444        /* NPIX/128 */
#define EPSBN  1e-5f

typedef __bf16 bf16x8 __attribute__((ext_vector_type(8)));
typedef float  f32x4  __attribute__((ext_vector_type(4)));

__device__ __forceinline__ u16 f2bf(float f) {
  u32 u = __float_as_uint(f);
  u += 0x7fffu + ((u >> 16) & 1u);          // round-to-nearest-even
  return (u16)(u >> 16);
}
__device__ __forceinline__ float bf2f(u16 v) {
  return __uint_as_float(((u32)v) << 16);
}

// ---------------- kernel 0: W -> bf16 [768][256] plain rows, bias, zero stats
__global__ __launch_bounds__(256) void k_prep(
    const float* __restrict__ Wq, const float* __restrict__ bq,
    const float* __restrict__ Wk, const float* __restrict__ bk,
    const float* __restrict__ Wv, const float* __restrict__ bv,
    u16* __restrict__ Wall, float* __restrict__ ball, float* __restrict__ stats) {
  const int n = blockIdx.x, t = threadIdx.x;
  const float* src; const float* bs; int r;
  if (n < 256)      { src = Wq; bs = bq; r = n; }
  else if (n < 512) { src = Wk; bs = bk; r = n - 256; }
  else              { src = Wv; bs = bv; r = n - 512; }
  Wall[n * 256 + t] = f2bf(src[r * 256 + t]);
  if (t == 0) ball[n] = bs[r];
  if (n == 0) { for (int i = t; i < 1536; i += 256) stats[i] = 0.f; }
}

// ---------------- kernel 0b: x [B][256][361] f32 -> xT [NPIX][256] bf16, ROTATED columns
// logical 16B granule g stored at physical slot (g + 4*(m&7)) & 31
__global__ __launch_bounds__(384) void k_xt(const float* __restrict__ x, u16* __restrict__ xT) {
  const int bb = blockIdx.x, t = threadIdx.x;
  if (t >= HW) return;
  const size_t m = (size_t)bb * HW + t;
  const float* xp = x + (size_t)bb * INC * HW + t;
  char* dst = (char*)xT + m * 512;
  const int rot = ((int)m & 7) * 4;
  #pragma unroll 1
  for (int cc = 0; cc < INC; cc += 32) {
    __align__(16) u16 tmp[32];
    #pragma unroll
    for (int c = 0; c < 32; ++c) tmp[c] = f2bf(xp[(size_t)(cc + c) * HW]);
    #pragma unroll
    for (int p = 0; p < 4; ++p) {
      int slot = ((cc >> 3) + p + rot) & 31;
      *(uint4*)(dst + slot * 16) = ((const uint4*)tmp)[p];
    }
  }
}

// ---------------- kernel 1: QKV GEMM (A=x from LDS, B=W from L2), 8 waves
// outputs all in [bh][px][32c] layout; lanes carry channels -> contiguous stores
__global__ __launch_bounds__(512, 4) void k_gemm(
    const u16* __restrict__ xT, const u16* __restrict__ Wall,
    const float* __restrict__ ball,
    u16* __restrict__ qQ, u16* __restrict__ qK, u16* __restrict__ qV,
    float* __restrict__ stats) {
  __shared__ u16   Al[128 * 256];                  // 64 KB, rotated rows
  __shared__ float bl[NTOT];
  const int tid = threadIdx.x;
  const int m0  = blockIdx.x * 128;
  {
    const uint4* src = (const uint4*)(xT + (size_t)m0 * 256);
    uint4* dst = (uint4*)Al;
    #pragma unroll
    for (int i = tid; i < 4096; i += 512) dst[i] = src[i];
  }
  for (int i = tid; i < NTOT; i += 512) bl[i] = ball[i];
  __syncthreads();

  const int lane = tid & 63, w = tid >> 6;
  const int wM = w & 1, wN = w >> 1;               // 2 M-halves x 4 N-quarters
  const int l15 = lane & 15, kq = lane >> 4;

  // per-thread 16 output px rows -> store bases: bb*92416 + pxl*32
  int rQ[16];
  #pragma unroll
  for (int mi = 0; mi < 4; ++mi)
    #pragma unroll
    for (int j = 0; j < 4; ++j) {
      int pg = m0 + wM * 64 + mi * 16 + kq * 4 + j;
      int bb = pg / 361, pxl = pg - bb * 361;
      rQ[mi * 4 + j] = bb * 92416 + pxl * 32;
    }
  // A-fragment LDS row bases (row on l15) and rotated start column
  int rowb[4];
  #pragma unroll
  for (int mi = 0; mi < 4; ++mi) rowb[mi] = (wM * 64 + mi * 16 + l15) * 512;
  const int col0 = (kq * 16 + (l15 & 7) * 64) & 511;
  const char* Alb = (const char*)Al;
  const int chw = wN * 64;                         // wave's channel base (0..255)

  #pragma unroll 1
  for (int nt = 0; nt < 3; ++nt) {
    f32x4 acc[4][4];
    #pragma unroll
    for (int i = 0; i < 4; ++i)
      #pragma unroll
      for (int j = 0; j < 4; ++j) acc[i][j] = (f32x4){0.f, 0.f, 0.f, 0.f};

    const char* wrow[4];
    #pragma unroll
    for (int ni = 0; ni < 4; ++ni)
      wrow[ni] = (const char*)Wall + (size_t)(nt * 256 + chw + ni * 16 + l15) * 512 + kq * 16;

    int col = col0;
    #pragma unroll
    for (int ks = 0; ks < 8; ++ks) {
      bf16x8 a[4], b[4];
      #pragma unroll
      for (int ni = 0; ni < 4; ++ni)
        b[ni] = __builtin_bit_cast(bf16x8, *(const uint4*)(wrow[ni] + ks * 64));
      #pragma unroll
      for (int mi = 0; mi < 4; ++mi)
        a[mi] = __builtin_bit_cast(bf16x8, *(const uint4*)(Alb + rowb[mi] + col));
      col = (col + 64) & 511;
      #pragma unroll
      for (int mi = 0; mi < 4; ++mi)
        #pragma unroll
        for (int ni = 0; ni < 4; ++ni)
          acc[mi][ni] = __builtin_amdgcn_mfma_f32_16x16x32_bf16(a[mi], b[ni], acc[mi][ni], 0, 0, 0);
    }

    u16* qp = (nt == 0) ? qQ : (nt == 1) ? qK : qV;
    #pragma unroll
    for (int ni = 0; ni < 4; ++ni) {
      const int ch  = chw + ni * 16 + l15;               // 0..255, lane-contiguous
      const int hof = (ch >> 5) * 11552 + (ch & 31);     // h*32*361 + c
      const int n   = nt * 256 + ch;
      const float bias = bl[n];
      float s = 0.f, q = 0.f;
      #pragma unroll
      for (int r = 0; r < 16; ++r) {
        float v = acc[r >> 2][ni][r & 3] + bias;
        qp[rQ[r] + hof] = f2bf(v);
        s += v; q += v * v;
      }
      s += __shfl_down(s, 32);  q += __shfl_down(q, 32);
      s += __shfl_down(s, 16);  q += __shfl_down(q, 16);
      if (kq == 0) {
        atomicAdd(&stats[n], s);
        atomicAdd(&stats[NTOT + n], q);
      }
    }
  }
}

// ---------------- kernel 2: finalize BN -> s_all, t_all
__global__ void k_stats(const float* __restrict__ stats,
                        const float* __restrict__ gQ, const float* __restrict__ betaQ,
                        const float* __restrict__ gK, const float* __restrict__ betaK,
                        const float* __restrict__ gV, const float* __restrict__ betaV,
                        float* __restrict__ s_all, float* __restrict__ t_all) {
  const int n = threadIdx.x;
  if (n >= NTOT) return;
  const float invP = 1.f / (float)NPIX;
  float mean = stats[n] * invP;
  float var  = stats[NTOT + n] * invP - mean * mean;
  float g, be;
  if (n < 256)      { g = gQ[n];       be = betaQ[n]; }
  else if (n < 512) { g = gK[n - 256]; be = betaK[n - 256]; }
  else              { g = gV[n - 512]; be = betaV[n - 512]; }
  float s = g * rsqrtf(var + EPSBN);
  s_all[n] = s;
  t_all[n] = be - s * mean;
}

// ---------------- kernel 3: neighbor attention + softmax + ReLU + residual
// one block per (bb,h); K then V phase-share one 23KB LDS buffer (transposed on stage)
__global__ __launch_bounds__(384, 6) void k_attn(
    const u16* __restrict__ qQ, const u16* __restrict__ qK, const u16* __restrict__ qV,
    const float* __restrict__ s_all, const float* __restrict__ t_all,
    const float* __restrict__ x, float* __restrict__ out) {
  __shared__ __align__(16) u16 KV[32 * HW];          // [c][px]
  __shared__ float sQ[32], tQ[32], sK[32], tK[32], sV[32], tV[32];
  const int bb = blockIdx.x, h = blockIdx.y, tid = threadIdx.x;
  const int bh = bb * NHEADS + h;

  if (tid < 96) {
    int which = tid >> 5, c = tid & 31;
    float sv = s_all[which * 256 + h * 32 + c];
    float tv = t_all[which * 256 + h * 32 + c];
    if (which == 0)      { sQ[c] = sv; tQ[c] = tv; }
    else if (which == 1) { sK[c] = sv; tK[c] = tv; }
    else                 { sV[c] = sv; tV[c] = tv; }
  }
  // stage K: contiguous read [px][c], transpose into LDS [c][px]
  {
    const uint4* gk = (const uint4*)(qK + (size_t)bh * 11552);
    for (int i = tid; i < 1444; i += 384) {
      uint4 kk = gk[i];
      int px = i >> 2, c0 = (i & 3) << 3;
      u16* d = KV + c0 * HW + px;
      d[0 * HW] = (u16)(kk.x & 0xffffu); d[1 * HW] = (u16)(kk.x >> 16);
      d[2 * HW] = (u16)(kk.y & 0xffffu); d[3 * HW] = (u16)(kk.y >> 16);
      d[4 * HW] = (u16)(kk.z & 0xffffu); d[5 * HW] = (u16)(kk.z >> 16);
      d[6 * HW] = (u16)(kk.w & 0xffffu); d[7 * HW] = (u16)(kk.w >> 16);
    }
  }
  __syncthreads();

  const int px = tid;
  const bool act = tid < HW;
  float a0 = 0.f, a1 = 0.f, a2 = 0.f, a3 = 0.f;
  int pn0 = 0, pn1 = 0, pn2 = 0, pn3 = 0;
  if (act) {
    const int yy = px / 19, xx = px - yy * 19;
    const bool i0 = yy > 0, i1 = yy < 18, i2 = xx > 0, i3 = xx < 18;
    pn0 = i0 ? px - 19 : px;  pn1 = i1 ? px + 19 : px;
    pn2 = i2 ? px - 1  : px;  pn3 = i3 ? px + 1  : px;
    const u16* K0 = KV + pn0; const u16* K1 = KV + pn1;
    const u16* K2 = KV + pn2; const u16* K3 = KV + pn3;
    const uint4* q4 = (const uint4*)(qQ + ((size_t)bh * HW + px) * 32);
    uint4 qA = q4[0], qB = q4[1], qC = q4[2], qD = q4[3];
    float d0 = 0.f, d1 = 0.f, d2 = 0.f, d3 = 0.f, Ct = 0.f;
#define CH2(wrd, c0) { \
    float ql = bf2f((u16)((wrd) & 0xffffu)), qh = bf2f((u16)((wrd) >> 16)); \
    float qn0 = sQ[c0] * ql + tQ[c0]; \
    float qn1 = sQ[(c0)+1] * qh + tQ[(c0)+1]; \
    Ct += qn0 * tK[c0] + qn1 * tK[(c0)+1]; \
    float w0 = qn0 * sK[c0], w1 = qn1 * sK[(c0)+1]; \
    d0 += w0 * bf2f(K0[(c0)*HW]) + w1 * bf2f(K0[((c0)+1)*HW]); \
    d1 += w0 * bf2f(K1[(c0)*HW]) + w1 * bf2f(K1[((c0)+1)*HW]); \
    d2 += w0 * bf2f(K2[(c0)*HW]) + w1 * bf2f(K2[((c0)+1)*HW]); \
    d3 += w0 * bf2f(K3[(c0)*HW]) + w1 * bf2f(K3[((c0)+1)*HW]); \
  }
    CH2(qA.x, 0)  CH2(qA.y, 2)  CH2(qA.z, 4)  CH2(qA.w, 6)
    CH2(qB.x, 8)  CH2(qB.y, 10) CH2(qB.z, 12) CH2(qB.w, 14)
    CH2(qC.x, 16) CH2(qC.y, 18) CH2(qC.z, 20) CH2(qC.w, 22)
    CH2(qD.x, 24) CH2(qD.y, 26) CH2(qD.z, 28) CH2(qD.w, 30)
#undef CH2
    const float rs = 0.17677669529663687f;     // 1/sqrt(32)
    float l0 = i0 ? (d0 + Ct) * rs : 0.f;
    float l1 = i1 ? (d1 + Ct) * rs : 0.f;
    float l2 = i2 ? (d2 + Ct) * rs : 0.f;
    float l3 = i3 ? (d3 + Ct) * rs : 0.f;
    float mx = fmaxf(fmaxf(l0, l1), fmaxf(l2, l3));
    float e0 = __expf(l0 - mx), e1 = __expf(l1 - mx);
    float e2 = __expf(l2 - mx), e3 = __expf(l3 - mx);
    float inv = 1.f / (e0 + e1 + e2 + e3);
    a0 = i0 ? e0 * inv : 0.f;  a1 = i1 ? e1 * inv : 0.f;
    a2 = i2 ? e2 * inv : 0.f;  a3 = i3 ? e3 * inv : 0.f;
  }
  __syncthreads();
  // stage V over the same buffer (transposed)
  {
    const uint4* gv = (const uint4*)(qV + (size_t)bh * 11552);
    for (int i = tid; i < 1444; i += 384) {
      uint4 vv = gv[i];
      int pxs = i >> 2, c0 = (i & 3) << 3;
      u16* d = KV + c0 * HW + pxs;
      d[0 * HW] = (u16)(vv.x & 0xffffu); d[1 * HW] = (u16)(vv.x >> 16);
      d[2 * HW] = (u16)(vv.y & 0xffffu); d[3 * HW] = (u16)(vv.y >> 16);
      d[4 * HW] = (u16)(vv.z & 0xffffu); d[5 * HW] = (u16)(vv.z >> 16);
      d[6 * HW] = (u16)(vv.w & 0xffffu); d[7 * HW] = (u16)(vv.w >> 16);
    }
  }
  __syncthreads();

  if (act) {
    const float ai = a0 + a1 + a2 + a3;
    const u16* V0 = KV + pn0; const u16* V1 = KV + pn1;
    const u16* V2 = KV + pn2; const u16* V3 = KV + pn3;
    const size_t gb = ((size_t)bb * 256 + h * 32) * HW + px;
    #pragma unroll
    for (int oc = 0; oc < 32; ++oc) {
      float v = a0 * bf2f(V0[oc * HW]) + a1 * bf2f(V1[oc * HW])
              + a2 * bf2f(V2[oc * HW]) + a3 * bf2f(V3[oc * HW]);
      float o = sV[oc] * v + tV[oc] * ai;
      o = fmaxf(o, 0.f);
      const size_t g = gb + (size_t)oc * HW;
      out[g] = o + x[g];
    }
  }
}

// ---------------- workspace layout
constexpr size_t OFF_XT    = 0;
constexpr size_t SZ_XT     = (size_t)NPIX * 512;
constexpr size_t OFF_WALL  = OFF_XT + SZ_XT;
constexpr size_t SZ_WALL   = (size_t)NTOT * 512;
constexpr size_t OFF_BALL  = OFF_WALL + SZ_WALL;
constexpr size_t OFF_STATS = OFF_BALL + NTOT * 4;
constexpr size_t OFF_SALL  = OFF_STATS + 2 * NTOT * 4;
constexpr size_t OFF_TALL  = OFF_SALL + NTOT * 4;
constexpr size_t OFF_QQ    = OFF_TALL + NTOT * 4;
constexpr size_t SZ_ONE    = (size_t)NPIX * 256 * 2;
constexpr size_t OFF_QK    = OFF_QQ + SZ_ONE;
constexpr size_t OFF_QV    = OFF_QK + SZ_ONE;
constexpr size_t WS_NEEDED = OFF_QV + SZ_ONE;

extern "C" void kernel_launch(void* const* d_in, const int* in_sizes, int n_in,
                              void* d_out, int out_size, void* d_ws, size_t ws_size,
                              hipStream_t stream) {
  (void)in_sizes; (void)n_in; (void)out_size;
  if (ws_size < WS_NEEDED) return;

  const float* x     = (const float*)d_in[0];
  const float* Wq    = (const float*)d_in[1];
  const float* bq    = (const float*)d_in[2];
  const float* Wk    = (const float*)d_in[3];
  const float* bk    = (const float*)d_in[4];
  const float* Wv    = (const float*)d_in[5];
  const float* bv    = (const float*)d_in[6];
  const float* gQ    = (const float*)d_in[7];
  const float* betaQ = (const float*)d_in[8];
  const float* gK    = (const float*)d_in[9];
  const float* betaK = (const float*)d_in[10];
  const float* gV    = (const float*)d_in[11];
  const float* betaV = (const float*)d_in[12];
  float* out = (float*)d_out;

  char* w = (char*)d_ws;
  u16*   xT    = (u16*)(w + OFF_XT);
  u16*   Wall  = (u16*)(w + OFF_WALL);
  float* ball  = (float*)(w + OFF_BALL);
  float* stats = (float*)(w + OFF_STATS);
  float* s_all = (float*)(w + OFF_SALL);
  float* t_all = (float*)(w + OFF_TALL);
  u16*   qQ    = (u16*)(w + OFF_QQ);
  u16*   qK    = (u16*)(w + OFF_QK);
  u16*   qV    = (u16*)(w + OFF_QV);

  k_prep<<<NTOT, 256, 0, stream>>>(Wq, bq, Wk, bk, Wv, bv, Wall, ball, stats);
  k_xt<<<NB, 384, 0, stream>>>(x, xT);
  k_gemm<<<NWG_M, 512, 0, stream>>>(xT, Wall, ball, qQ, qK, qV, stats);
  k_stats<<<1, NTOT, 0, stream>>>(stats, gQ, betaQ, gK, betaK, gV, betaV, s_all, t_all);
  k_attn<<<dim3(NB, NHEADS), 384, 0, stream>>>(qQ, qK, qV, s_all, t_all, x, out);
}

// Round 5
// 495.798 us; speedup vs baseline: 1.8661x; 1.4255x over previous
//
#include <hip/hip_runtime.h>

typedef unsigned short u16;
typedef unsigned int   u32;

#define NB     512
#define INC    256
#define NHEADS 8
#define HW     361
#define NPIX   184832      /* NB*HW */
#define NTOT   768
#define NWG_M  1444        /* NPIX/128 */
#define EPSBN  1e-5f

typedef __bf16 bf16x8 __attribute__((ext_vector_type(8)));
typedef float  f32x4  __attribute__((ext_vector_type(4)));

__device__ __forceinline__ u16 f2bf(float f) {
  u32 u = __float_as_uint(f);
  u += 0x7fffu + ((u >> 16) & 1u);          // round-to-nearest-even
  return (u16)(u >> 16);
}
__device__ __forceinline__ float bf2f(u16 v) {
  return __uint_as_float(((u32)v) << 16);
}

// ---------------- kernel 0: W -> bf16 [768][256] plain rows, bias, zero stats
__global__ __launch_bounds__(256) void k_prep(
    const float* __restrict__ Wq, const float* __restrict__ bq,
    const float* __restrict__ Wk, const float* __restrict__ bk,
    const float* __restrict__ Wv, const float* __restrict__ bv,
    u16* __restrict__ Wall, float* __restrict__ ball, float* __restrict__ stats) {
  const int n = blockIdx.x, t = threadIdx.x;
  const float* src; const float* bs; int r;
  if (n < 256)      { src = Wq; bs = bq; r = n; }
  else if (n < 512) { src = Wk; bs = bk; r = n - 256; }
  else              { src = Wv; bs = bv; r = n - 512; }
  Wall[n * 256 + t] = f2bf(src[r * 256 + t]);
  if (t == 0) ball[n] = bs[r];
  if (n == 0) { for (int i = t; i < 1536; i += 256) stats[i] = 0.f; }
}

// ---------------- kernel 0b: x [B][256][361] f32 -> xT [NPIX][256] bf16, ROTATED columns
// logical 16B granule g stored at physical slot (g + 4*(m&7)) & 31
__global__ __launch_bounds__(384) void k_xt(const float* __restrict__ x, u16* __restrict__ xT) {
  const int bb = blockIdx.x, t = threadIdx.x;
  if (t >= HW) return;
  const size_t m = (size_t)bb * HW + t;
  const float* xp = x + (size_t)bb * INC * HW + t;
  char* dst = (char*)xT + m * 512;
  const int rot = ((int)m & 7) * 4;
  #pragma unroll 1
  for (int cc = 0; cc < INC; cc += 32) {
    __align__(16) u16 tmp[32];
    #pragma unroll
    for (int c = 0; c < 32; ++c) tmp[c] = f2bf(xp[(size_t)(cc + c) * HW]);
    #pragma unroll
    for (int p = 0; p < 4; ++p) {
      int slot = ((cc >> 3) + p + rot) & 31;
      *(uint4*)(dst + slot * 16) = ((const uint4*)tmp)[p];
    }
  }
}

// ---------------- kernel 1: QKV GEMM (A=x from LDS, B=W from L2), 8 waves
// outputs all in [bh][px][32c] layout; lanes carry channels -> contiguous stores
__global__ __launch_bounds__(512) void k_gemm(
    const u16* __restrict__ xT, const u16* __restrict__ Wall,
    const float* __restrict__ ball,
    u16* __restrict__ qQ, u16* __restrict__ qK, u16* __restrict__ qV,
    float* __restrict__ stats) {
  __shared__ u16   Al[128 * 256];                  // 64 KB, rotated rows
  __shared__ float bl[NTOT];
  const int tid = threadIdx.x;
  const int m0  = blockIdx.x * 128;
  {
    const uint4* src = (const uint4*)(xT + (size_t)m0 * 256);
    uint4* dst = (uint4*)Al;
    #pragma unroll
    for (int i = tid; i < 4096; i += 512) dst[i] = src[i];
  }
  for (int i = tid; i < NTOT; i += 512) bl[i] = ball[i];
  __syncthreads();

  const int lane = tid & 63, w = tid >> 6;
  const int wM = w & 1, wN = w >> 1;               // 2 M-halves x 4 N-quarters
  const int l15 = lane & 15, kq = lane >> 4;

  // per-thread 16 output px rows -> store bases: bb*92416 + pxl*32
  int rQ[16];
  #pragma unroll
  for (int mi = 0; mi < 4; ++mi)
    #pragma unroll
    for (int j = 0; j < 4; ++j) {
      int pg = m0 + wM * 64 + mi * 16 + kq * 4 + j;
      int bb = pg / 361, pxl = pg - bb * 361;
      rQ[mi * 4 + j] = bb * 92416 + pxl * 32;
    }
  // A-fragment LDS row bases (row on l15) and rotated start column
  int rowb[4];
  #pragma unroll
  for (int mi = 0; mi < 4; ++mi) rowb[mi] = (wM * 64 + mi * 16 + l15) * 512;
  const int col0 = (kq * 16 + (l15 & 7) * 64) & 511;
  const char* Alb = (const char*)Al;
  const int chw = wN * 64;                         // wave's channel base (0..255)

  #pragma unroll 1
  for (int nt = 0; nt < 3; ++nt) {
    f32x4 acc[4][4];
    #pragma unroll
    for (int i = 0; i < 4; ++i)
      #pragma unroll
      for (int j = 0; j < 4; ++j) acc[i][j] = (f32x4){0.f, 0.f, 0.f, 0.f};

    const char* wrow[4];
    #pragma unroll
    for (int ni = 0; ni < 4; ++ni)
      wrow[ni] = (const char*)Wall + (size_t)(nt * 256 + chw + ni * 16 + l15) * 512 + kq * 16;

    int col = col0;
    #pragma unroll
    for (int ks = 0; ks < 8; ++ks) {
      bf16x8 a[4], b[4];
      #pragma unroll
      for (int ni = 0; ni < 4; ++ni)
        b[ni] = __builtin_bit_cast(bf16x8, *(const uint4*)(wrow[ni] + ks * 64));
      #pragma unroll
      for (int mi = 0; mi < 4; ++mi)
        a[mi] = __builtin_bit_cast(bf16x8, *(const uint4*)(Alb + rowb[mi] + col));
      col = (col + 64) & 511;
      #pragma unroll
      for (int mi = 0; mi < 4; ++mi)
        #pragma unroll
        for (int ni = 0; ni < 4; ++ni)
          acc[mi][ni] = __builtin_amdgcn_mfma_f32_16x16x32_bf16(a[mi], b[ni], acc[mi][ni], 0, 0, 0);
    }

    u16* qp = (nt == 0) ? qQ : (nt == 1) ? qK : qV;
    #pragma unroll
    for (int ni = 0; ni < 4; ++ni) {
      const int ch  = chw + ni * 16 + l15;               // 0..255, lane-contiguous
      const int hof = (ch >> 5) * 11552 + (ch & 31);     // h*32*361 + c
      const int n   = nt * 256 + ch;
      const float bias = bl[n];
      float s = 0.f, q = 0.f;
      #pragma unroll
      for (int r = 0; r < 16; ++r) {
        float v = acc[r >> 2][ni][r & 3] + bias;
        qp[rQ[r] + hof] = f2bf(v);
        s += v; q += v * v;
      }
      s += __shfl_down(s, 32);  q += __shfl_down(q, 32);
      s += __shfl_down(s, 16);  q += __shfl_down(q, 16);
      if (kq == 0) {
        atomicAdd(&stats[n], s);
        atomicAdd(&stats[NTOT + n], q);
      }
    }
  }
}

// ---------------- kernel 2: finalize BN -> s_all, t_all
__global__ void k_stats(const float* __restrict__ stats,
                        const float* __restrict__ gQ, const float* __restrict__ betaQ,
                        const float* __restrict__ gK, const float* __restrict__ betaK,
                        const float* __restrict__ gV, const float* __restrict__ betaV,
                        float* __restrict__ s_all, float* __restrict__ t_all) {
  const int n = threadIdx.x;
  if (n >= NTOT) return;
  const float invP = 1.f / (float)NPIX;
  float mean = stats[n] * invP;
  float var  = stats[NTOT + n] * invP - mean * mean;
  float g, be;
  if (n < 256)      { g = gQ[n];       be = betaQ[n]; }
  else if (n < 512) { g = gK[n - 256]; be = betaK[n - 256]; }
  else              { g = gV[n - 512]; be = betaV[n - 512]; }
  float s = g * rsqrtf(var + EPSBN);
  s_all[n] = s;
  t_all[n] = be - s * mean;
}

// ---------------- kernel 3: neighbor attention + softmax + ReLU + residual
// one block per (bb,h); K then V phase-share one 23KB LDS buffer (transposed on stage)
__global__ __launch_bounds__(384, 6) void k_attn(
    const u16* __restrict__ qQ, const u16* __restrict__ qK, const u16* __restrict__ qV,
    const float* __restrict__ s_all, const float* __restrict__ t_all,
    const float* __restrict__ x, float* __restrict__ out) {
  __shared__ __align__(16) u16 KV[32 * HW];          // [c][px]
  __shared__ float sQ[32], tQ[32], sK[32], tK[32], sV[32], tV[32];
  const int bb = blockIdx.x, h = blockIdx.y, tid = threadIdx.x;
  const int bh = bb * NHEADS + h;

  if (tid < 96) {
    int which = tid >> 5, c = tid & 31;
    float sv = s_all[which * 256 + h * 32 + c];
    float tv = t_all[which * 256 + h * 32 + c];
    if (which == 0)      { sQ[c] = sv; tQ[c] = tv; }
    else if (which == 1) { sK[c] = sv; tK[c] = tv; }
    else                 { sV[c] = sv; tV[c] = tv; }
  }
  // stage K: contiguous read [px][c], transpose into LDS [c][px]
  {
    const uint4* gk = (const uint4*)(qK + (size_t)bh * 11552);
    for (int i = tid; i < 1444; i += 384) {
      uint4 kk = gk[i];
      int px = i >> 2, c0 = (i & 3) << 3;
      u16* d = KV + c0 * HW + px;
      d[0 * HW] = (u16)(kk.x & 0xffffu); d[1 * HW] = (u16)(kk.x >> 16);
      d[2 * HW] = (u16)(kk.y & 0xffffu); d[3 * HW] = (u16)(kk.y >> 16);
      d[4 * HW] = (u16)(kk.z & 0xffffu); d[5 * HW] = (u16)(kk.z >> 16);
      d[6 * HW] = (u16)(kk.w & 0xffffu); d[7 * HW] = (u16)(kk.w >> 16);
    }
  }
  __syncthreads();

  const int px = tid;
  const bool act = tid < HW;
  float a0 = 0.f, a1 = 0.f, a2 = 0.f, a3 = 0.f;
  int pn0 = 0, pn1 = 0, pn2 = 0, pn3 = 0;
  if (act) {
    const int yy = px / 19, xx = px - yy * 19;
    const bool i0 = yy > 0, i1 = yy < 18, i2 = xx > 0, i3 = xx < 18;
    pn0 = i0 ? px - 19 : px;  pn1 = i1 ? px + 19 : px;
    pn2 = i2 ? px - 1  : px;  pn3 = i3 ? px + 1  : px;
    const u16* K0 = KV + pn0; const u16* K1 = KV + pn1;
    const u16* K2 = KV + pn2; const u16* K3 = KV + pn3;
    const uint4* q4 = (const uint4*)(qQ + ((size_t)bh * HW + px) * 32);
    uint4 qA = q4[0], qB = q4[1], qC = q4[2], qD = q4[3];
    float d0 = 0.f, d1 = 0.f, d2 = 0.f, d3 = 0.f, Ct = 0.f;
#define CH2(wrd, c0) { \
    float ql = bf2f((u16)((wrd) & 0xffffu)), qh = bf2f((u16)((wrd) >> 16)); \
    float qn0 = sQ[c0] * ql + tQ[c0]; \
    float qn1 = sQ[(c0)+1] * qh + tQ[(c0)+1]; \
    Ct += qn0 * tK[c0] + qn1 * tK[(c0)+1]; \
    float w0 = qn0 * sK[c0], w1 = qn1 * sK[(c0)+1]; \
    d0 += w0 * bf2f(K0[(c0)*HW]) + w1 * bf2f(K0[((c0)+1)*HW]); \
    d1 += w0 * bf2f(K1[(c0)*HW]) + w1 * bf2f(K1[((c0)+1)*HW]); \
    d2 += w0 * bf2f(K2[(c0)*HW]) + w1 * bf2f(K2[((c0)+1)*HW]); \
    d3 += w0 * bf2f(K3[(c0)*HW]) + w1 * bf2f(K3[((c0)+1)*HW]); \
  }
    CH2(qA.x, 0)  CH2(qA.y, 2)  CH2(qA.z, 4)  CH2(qA.w, 6)
    CH2(qB.x, 8)  CH2(qB.y, 10) CH2(qB.z, 12) CH2(qB.w, 14)
    CH2(qC.x, 16) CH2(qC.y, 18) CH2(qC.z, 20) CH2(qC.w, 22)
    CH2(qD.x, 24) CH2(qD.y, 26) CH2(qD.z, 28) CH2(qD.w, 30)
#undef CH2
    const float rs = 0.17677669529663687f;     // 1/sqrt(32)
    float l0 = i0 ? (d0 + Ct) * rs : 0.f;
    float l1 = i1 ? (d1 + Ct) * rs : 0.f;
    float l2 = i2 ? (d2 + Ct) * rs : 0.f;
    float l3 = i3 ? (d3 + Ct) * rs : 0.f;
    float mx = fmaxf(fmaxf(l0, l1), fmaxf(l2, l3));
    float e0 = __expf(l0 - mx), e1 = __expf(l1 - mx);
    float e2 = __expf(l2 - mx), e3 = __expf(l3 - mx);
    float inv = 1.f / (e0 + e1 + e2 + e3);
    a0 = i0 ? e0 * inv : 0.f;  a1 = i1 ? e1 * inv : 0.f;
    a2 = i2 ? e2 * inv : 0.f;  a3 = i3 ? e3 * inv : 0.f;
  }
  __syncthreads();
  // stage V over the same buffer (transposed)
  {
    const uint4* gv = (const uint4*)(qV + (size_t)bh * 11552);
    for (int i = tid; i < 1444; i += 384) {
      uint4 vv = gv[i];
      int pxs = i >> 2, c0 = (i & 3) << 3;
      u16* d = KV + c0 * HW + pxs;
      d[0 * HW] = (u16)(vv.x & 0xffffu); d[1 * HW] = (u16)(vv.x >> 16);
      d[2 * HW] = (u16)(vv.y & 0xffffu); d[3 * HW] = (u16)(vv.y >> 16);
      d[4 * HW] = (u16)(vv.z & 0xffffu); d[5 * HW] = (u16)(vv.z >> 16);
      d[6 * HW] = (u16)(vv.w & 0xffffu); d[7 * HW] = (u16)(vv.w >> 16);
    }
  }
  __syncthreads();

  if (act) {
    const float ai = a0 + a1 + a2 + a3;
    const u16* V0 = KV + pn0; const u16* V1 = KV + pn1;
    const u16* V2 = KV + pn2; const u16* V3 = KV + pn3;
    const size_t gb = ((size_t)bb * 256 + h * 32) * HW + px;
    #pragma unroll
    for (int oc = 0; oc < 32; ++oc) {
      float v = a0 * bf2f(V0[oc * HW]) + a1 * bf2f(V1[oc * HW])
              + a2 * bf2f(V2[oc * HW]) + a3 * bf2f(V3[oc * HW]);
      float o = sV[oc] * v + tV[oc] * ai;
      o = fmaxf(o, 0.f);
      const size_t g = gb + (size_t)oc * HW;
      out[g] = o + x[g];
    }
  }
}

// ---------------- workspace layout
constexpr size_t OFF_XT    = 0;
constexpr size_t SZ_XT     = (size_t)NPIX * 512;
constexpr size_t OFF_WALL  = OFF_XT + SZ_XT;
constexpr size_t SZ_WALL   = (size_t)NTOT * 512;
constexpr size_t OFF_BALL  = OFF_WALL + SZ_WALL;
constexpr size_t OFF_STATS = OFF_BALL + NTOT * 4;
constexpr size_t OFF_SALL  = OFF_STATS + 2 * NTOT * 4;
constexpr size_t OFF_TALL  = OFF_SALL + NTOT * 4;
constexpr size_t OFF_QQ    = OFF_TALL + NTOT * 4;
constexpr size_t SZ_ONE    = (size_t)NPIX * 256 * 2;
constexpr size_t OFF_QK    = OFF_QQ + SZ_ONE;
constexpr size_t OFF_QV    = OFF_QK + SZ_ONE;
constexpr size_t WS_NEEDED = OFF_QV + SZ_ONE;

extern "C" void kernel_launch(void* const* d_in, const int* in_sizes, int n_in,
                              void* d_out, int out_size, void* d_ws, size_t ws_size,
                              hipStream_t stream) {
  (void)in_sizes; (void)n_in; (void)out_size;
  if (ws_size < WS_NEEDED) return;

  const float* x     = (const float*)d_in[0];
  const float* Wq    = (const float*)d_in[1];
  const float* bq    = (const float*)d_in[2];
  const float* Wk    = (const float*)d_in[3];
  const float* bk    = (const float*)d_in[4];
  const float* Wv    = (const float*)d_in[5];
  const float* bv    = (const float*)d_in[6];
  const float* gQ    = (const float*)d_in[7];
  const float* betaQ = (const float*)d_in[8];
  const float* gK    = (const float*)d_in[9];
  const float* betaK = (const float*)d_in[10];
  const float* gV    = (const float*)d_in[11];
  const float* betaV = (const float*)d_in[12];
  float* out = (float*)d_out;

  char* w = (char*)d_ws;
  u16*   xT    = (u16*)(w + OFF_XT);
  u16*   Wall  = (u16*)(w + OFF_WALL);
  float* ball  = (float*)(w + OFF_BALL);
  float* stats = (float*)(w + OFF_STATS);
  float* s_all = (float*)(w + OFF_SALL);
  float* t_all = (float*)(w + OFF_TALL);
  u16*   qQ    = (u16*)(w + OFF_QQ);
  u16*   qK    = (u16*)(w + OFF_QK);
  u16*   qV    = (u16*)(w + OFF_QV);

  k_prep<<<NTOT, 256, 0, stream>>>(Wq, bq, Wk, bk, Wv, bv, Wall, ball, stats);
  k_xt<<<NB, 384, 0, stream>>>(x, xT);
  k_gemm<<<NWG_M, 512, 0, stream>>>(xT, Wall, ball, qQ, qK, qV, stats);
  k_stats<<<1, NTOT, 0, stream>>>(stats, gQ, betaQ, gK, betaK, gV, betaV, s_all, t_all);
  k_attn<<<dim3(NB, NHEADS), 384, 0, stream>>>(qQ, qK, qV, s_all, t_all, x, out);
}

// Round 6
// 493.140 us; speedup vs baseline: 1.8762x; 1.0054x over previous
//
#include <hip/hip_runtime.h>

typedef unsigned short u16;
typedef unsigned int   u32;

#define NB     512
#define INC    256
#define NHEADS 8
#define HW     361
#define NPIX   184832      /* NB*HW */
#define NTOT   768
#define EPSBN  1e-5f

typedef __bf16 bf16x8 __attribute__((ext_vector_type(8)));
typedef float  f32x4  __attribute__((ext_vector_type(4)));

__device__ __forceinline__ u16 f2bf(float f) {
  u32 u = __float_as_uint(f);
  u += 0x7fffu + ((u >> 16) & 1u);          // round-to-nearest-even
  return (u16)(u >> 16);
}
__device__ __forceinline__ float bf2f(u16 v) {
  return __uint_as_float(((u32)v) << 16);
}

// ---------------- kernel 0: W -> bf16 [768][256] plain rows, bias, zero stats
__global__ __launch_bounds__(256) void k_prep(
    const float* __restrict__ Wq, const float* __restrict__ bq,
    const float* __restrict__ Wk, const float* __restrict__ bk,
    const float* __restrict__ Wv, const float* __restrict__ bv,
    u16* __restrict__ Wall, float* __restrict__ ball, float* __restrict__ stats) {
  const int n = blockIdx.x, t = threadIdx.x;
  const float* src; const float* bs; int r;
  if (n < 256)      { src = Wq; bs = bq; r = n; }
  else if (n < 512) { src = Wk; bs = bk; r = n - 256; }
  else              { src = Wv; bs = bv; r = n - 512; }
  Wall[n * 256 + t] = f2bf(src[r * 256 + t]);
  if (t == 0) ball[n] = bs[r];
  if (n == 0) { for (int i = t; i < 1536; i += 256) stats[i] = 0.f; }
}

// ---------------- kernel 0b: x [B][256][361] f32 -> xT [NPIX][256] bf16, ROTATED columns
// logical 16B granule g stored at physical slot (g + 4*(m&7)) & 31
__global__ __launch_bounds__(384) void k_xt(const float* __restrict__ x, u16* __restrict__ xT) {
  const int bb = blockIdx.x, t = threadIdx.x;
  if (t >= HW) return;
  const size_t m = (size_t)bb * HW + t;
  const float* xp = x + (size_t)bb * INC * HW + t;
  char* dst = (char*)xT + m * 512;
  const int rot = ((int)m & 7) * 4;
  #pragma unroll 1
  for (int cc = 0; cc < INC; cc += 32) {
    __align__(16) u16 tmp[32];
    #pragma unroll
    for (int c = 0; c < 32; ++c) tmp[c] = f2bf(xp[(size_t)(cc + c) * HW]);
    #pragma unroll
    for (int p = 0; p < 4; ++p) {
      int slot = ((cc >> 3) + p + rot) & 31;
      *(uint4*)(dst + slot * 16) = ((const uint4*)tmp)[p];
    }
  }
}

// ---------------- kernel 1: QKV GEMM, M-tile 64 (per-image), 8 waves, 32KB LDS
// wave w owns head w's 32 channels; outputs [bh][px][32c]; lanes carry channels
__global__ __launch_bounds__(512) void k_gemm(
    const u16* __restrict__ xT, const u16* __restrict__ Wall,
    const float* __restrict__ ball,
    u16* __restrict__ qQ, u16* __restrict__ qK, u16* __restrict__ qV,
    float* __restrict__ stats) {
  __shared__ u16   Al[64 * 256];                   // 32 KB, rotated rows
  __shared__ float bl[NTOT];
  const int tid = threadIdx.x;
  const int tx  = blockIdx.x;                      // 0..5 tile-in-image
  const int bb  = blockIdx.y;
  const int px0 = tx * 64;
  const int nvalid = (px0 + 64 <= HW) ? 64 : (HW - px0);   // 64 or 41
  {
    uint4* dst = (uint4*)Al;
    const uint4* src = (const uint4*)(xT + ((size_t)bb * HW + px0) * 256);
    #pragma unroll
    for (int i = 0; i < 4; ++i) {
      int idx = tid + i * 512;                     // 0..2047, 32 uint4 per row
      int row = idx >> 5;
      dst[idx] = (row < nvalid) ? src[idx] : make_uint4(0u, 0u, 0u, 0u);
    }
  }
  for (int i = tid; i < NTOT; i += 512) bl[i] = ball[i];
  __syncthreads();

  const int lane = tid & 63, w = tid >> 6;         // w = wave = head 0..7
  const int l15 = lane & 15, kq = lane >> 4;
  // xT rotation depends on m&7 = (bb*361+px0+row)&7 = (bb+row)&7 ; row≡l15 (mod 8)
  const int col0 = ((kq * 16) + (((l15 + bb) & 7) * 64)) & 511;
  const char* Alb = (const char*)Al;
  const size_t obh = ((size_t)bb * NHEADS + w) * (32 * HW);   // output head base

  #pragma unroll 1
  for (int nt = 0; nt < 3; ++nt) {
    f32x4 acc[4][2];
    #pragma unroll
    for (int i = 0; i < 4; ++i) { acc[i][0] = (f32x4){0.f,0.f,0.f,0.f}; acc[i][1] = (f32x4){0.f,0.f,0.f,0.f}; }

    const char* wrow0 = (const char*)Wall + (size_t)(nt * 256 + w * 32 + l15) * 512 + kq * 16;
    const char* wrow1 = wrow0 + 16 * 512;

    int col = col0;
    #pragma unroll
    for (int ks = 0; ks < 8; ++ks) {
      bf16x8 b0 = __builtin_bit_cast(bf16x8, *(const uint4*)(wrow0 + ks * 64));
      bf16x8 b1 = __builtin_bit_cast(bf16x8, *(const uint4*)(wrow1 + ks * 64));
      bf16x8 a[4];
      #pragma unroll
      for (int mi = 0; mi < 4; ++mi)
        a[mi] = __builtin_bit_cast(bf16x8, *(const uint4*)(Alb + (mi * 16 + l15) * 512 + col));
      col = (col + 64) & 511;
      #pragma unroll
      for (int mi = 0; mi < 4; ++mi) {
        acc[mi][0] = __builtin_amdgcn_mfma_f32_16x16x32_bf16(a[mi], b0, acc[mi][0], 0, 0, 0);
        acc[mi][1] = __builtin_amdgcn_mfma_f32_16x16x32_bf16(a[mi], b1, acc[mi][1], 0, 0, 0);
      }
    }

    u16* qp = (nt == 0) ? qQ : (nt == 1) ? qK : qV;
    #pragma unroll
    for (int ni = 0; ni < 2; ++ni) {
      const int c = ni * 16 + l15;                 // 0..31 within head
      const int n = nt * 256 + w * 32 + c;
      const float bias = bl[n];
      float s = 0.f, q = 0.f;
      #pragma unroll
      for (int mi = 0; mi < 4; ++mi) {
        #pragma unroll
        for (int j = 0; j < 4; ++j) {
          const int pxr = mi * 16 + kq * 4 + j;    // row in tile
          if (pxr < nvalid) {
            float v = acc[mi][ni][j] + bias;
            qp[obh + (size_t)(px0 + pxr) * 32 + c] = f2bf(v);
            s += v; q += v * v;
          }
        }
      }
      s += __shfl_down(s, 32);  q += __shfl_down(q, 32);
      s += __shfl_down(s, 16);  q += __shfl_down(q, 16);
      if (kq == 0) {
        atomicAdd(&stats[n], s);
        atomicAdd(&stats[NTOT + n], q);
      }
    }
  }
}

// ---------------- kernel 2: finalize BN -> s_all, t_all
__global__ void k_stats(const float* __restrict__ stats,
                        const float* __restrict__ gQ, const float* __restrict__ betaQ,
                        const float* __restrict__ gK, const float* __restrict__ betaK,
                        const float* __restrict__ gV, const float* __restrict__ betaV,
                        float* __restrict__ s_all, float* __restrict__ t_all) {
  const int n = threadIdx.x;
  if (n >= NTOT) return;
  const float invP = 1.f / (float)NPIX;
  float mean = stats[n] * invP;
  float var  = stats[NTOT + n] * invP - mean * mean;
  float g, be;
  if (n < 256)      { g = gQ[n];       be = betaQ[n]; }
  else if (n < 512) { g = gK[n - 256]; be = betaK[n - 256]; }
  else              { g = gV[n - 512]; be = betaV[n - 512]; }
  float s = g * rsqrtf(var + EPSBN);
  s_all[n] = s;
  t_all[n] = be - s * mean;
}

// ---------------- kernel 3: neighbor attention + softmax + ReLU + residual
// one block per (bb,h); K then V phase-share one 23KB LDS buffer (transposed on stage)
__global__ __launch_bounds__(384, 6) void k_attn(
    const u16* __restrict__ qQ, const u16* __restrict__ qK, const u16* __restrict__ qV,
    const float* __restrict__ s_all, const float* __restrict__ t_all,
    const float* __restrict__ x, float* __restrict__ out) {
  __shared__ __align__(16) u16 KV[32 * HW];          // [c][px]
  __shared__ float sQ[32], tQ[32], sK[32], tK[32], sV[32], tV[32];
  const int bb = blockIdx.x, h = blockIdx.y, tid = threadIdx.x;
  const int bh = bb * NHEADS + h;

  if (tid < 96) {
    int which = tid >> 5, c = tid & 31;
    float sv = s_all[which * 256 + h * 32 + c];
    float tv = t_all[which * 256 + h * 32 + c];
    if (which == 0)      { sQ[c] = sv; tQ[c] = tv; }
    else if (which == 1) { sK[c] = sv; tK[c] = tv; }
    else                 { sV[c] = sv; tV[c] = tv; }
  }
  // stage K: contiguous read [px][c], transpose into LDS [c][px]
  {
    const uint4* gk = (const uint4*)(qK + (size_t)bh * 11552);
    for (int i = tid; i < 1444; i += 384) {
      uint4 kk = gk[i];
      int px = i >> 2, c0 = (i & 3) << 3;
      u16* d = KV + c0 * HW + px;
      d[0 * HW] = (u16)(kk.x & 0xffffu); d[1 * HW] = (u16)(kk.x >> 16);
      d[2 * HW] = (u16)(kk.y & 0xffffu); d[3 * HW] = (u16)(kk.y >> 16);
      d[4 * HW] = (u16)(kk.z & 0xffffu); d[5 * HW] = (u16)(kk.z >> 16);
      d[6 * HW] = (u16)(kk.w & 0xffffu); d[7 * HW] = (u16)(kk.w >> 16);
    }
  }
  __syncthreads();

  const int px = tid;
  const bool act = tid < HW;
  float a0 = 0.f, a1 = 0.f, a2 = 0.f, a3 = 0.f;
  int pn0 = 0, pn1 = 0, pn2 = 0, pn3 = 0;
  if (act) {
    const int yy = px / 19, xx = px - yy * 19;
    const bool i0 = yy > 0, i1 = yy < 18, i2 = xx > 0, i3 = xx < 18;
    pn0 = i0 ? px - 19 : px;  pn1 = i1 ? px + 19 : px;
    pn2 = i2 ? px - 1  : px;  pn3 = i3 ? px + 1  : px;
    const u16* K0 = KV + pn0; const u16* K1 = KV + pn1;
    const u16* K2 = KV + pn2; const u16* K3 = KV + pn3;
    const uint4* q4 = (const uint4*)(qQ + ((size_t)bh * HW + px) * 32);
    uint4 qA = q4[0], qB = q4[1], qC = q4[2], qD = q4[3];
    float d0 = 0.f, d1 = 0.f, d2 = 0.f, d3 = 0.f, Ct = 0.f;
#define CH2(wrd, c0) { \
    float ql = bf2f((u16)((wrd) & 0xffffu)), qh = bf2f((u16)((wrd) >> 16)); \
    float qn0 = sQ[c0] * ql + tQ[c0]; \
    float qn1 = sQ[(c0)+1] * qh + tQ[(c0)+1]; \
    Ct += qn0 * tK[c0] + qn1 * tK[(c0)+1]; \
    float w0 = qn0 * sK[c0], w1 = qn1 * sK[(c0)+1]; \
    d0 += w0 * bf2f(K0[(c0)*HW]) + w1 * bf2f(K0[((c0)+1)*HW]); \
    d1 += w0 * bf2f(K1[(c0)*HW]) + w1 * bf2f(K1[((c0)+1)*HW]); \
    d2 += w0 * bf2f(K2[(c0)*HW]) + w1 * bf2f(K2[((c0)+1)*HW]); \
    d3 += w0 * bf2f(K3[(c0)*HW]) + w1 * bf2f(K3[((c0)+1)*HW]); \
  }
    CH2(qA.x, 0)  CH2(qA.y, 2)  CH2(qA.z, 4)  CH2(qA.w, 6)
    CH2(qB.x, 8)  CH2(qB.y, 10) CH2(qB.z, 12) CH2(qB.w, 14)
    CH2(qC.x, 16) CH2(qC.y, 18) CH2(qC.z, 20) CH2(qC.w, 22)
    CH2(qD.x, 24) CH2(qD.y, 26) CH2(qD.z, 28) CH2(qD.w, 30)
#undef CH2
    const float rs = 0.17677669529663687f;     // 1/sqrt(32)
    float l0 = i0 ? (d0 + Ct) * rs : 0.f;
    float l1 = i1 ? (d1 + Ct) * rs : 0.f;
    float l2 = i2 ? (d2 + Ct) * rs : 0.f;
    float l3 = i3 ? (d3 + Ct) * rs : 0.f;
    float mx = fmaxf(fmaxf(l0, l1), fmaxf(l2, l3));
    float e0 = __expf(l0 - mx), e1 = __expf(l1 - mx);
    float e2 = __expf(l2 - mx), e3 = __expf(l3 - mx);
    float inv = 1.f / (e0 + e1 + e2 + e3);
    a0 = i0 ? e0 * inv : 0.f;  a1 = i1 ? e1 * inv : 0.f;
    a2 = i2 ? e2 * inv : 0.f;  a3 = i3 ? e3 * inv : 0.f;
  }
  __syncthreads();
  // stage V over the same buffer (transposed)
  {
    const uint4* gv = (const uint4*)(qV + (size_t)bh * 11552);
    for (int i = tid; i < 1444; i += 384) {
      uint4 vv = gv[i];
      int pxs = i >> 2, c0 = (i & 3) << 3;
      u16* d = KV + c0 * HW + pxs;
      d[0 * HW] = (u16)(vv.x & 0xffffu); d[1 * HW] = (u16)(vv.x >> 16);
      d[2 * HW] = (u16)(vv.y & 0xffffu); d[3 * HW] = (u16)(vv.y >> 16);
      d[4 * HW] = (u16)(vv.z & 0xffffu); d[5 * HW] = (u16)(vv.z >> 16);
      d[6 * HW] = (u16)(vv.w & 0xffffu); d[7 * HW] = (u16)(vv.w >> 16);
    }
  }
  __syncthreads();

  if (act) {
    const float ai = a0 + a1 + a2 + a3;
    const u16* V0 = KV + pn0; const u16* V1 = KV + pn1;
    const u16* V2 = KV + pn2; const u16* V3 = KV + pn3;
    const size_t gb = ((size_t)bb * 256 + h * 32) * HW + px;
    #pragma unroll
    for (int oc = 0; oc < 32; ++oc) {
      float v = a0 * bf2f(V0[oc * HW]) + a1 * bf2f(V1[oc * HW])
              + a2 * bf2f(V2[oc * HW]) + a3 * bf2f(V3[oc * HW]);
      float o = sV[oc] * v + tV[oc] * ai;
      o = fmaxf(o, 0.f);
      const size_t g = gb + (size_t)oc * HW;
      out[g] = o + x[g];
    }
  }
}

// ---------------- workspace layout
constexpr size_t OFF_XT    = 0;
constexpr size_t SZ_XT     = (size_t)NPIX * 512;
constexpr size_t OFF_WALL  = OFF_XT + SZ_XT;
constexpr size_t SZ_WALL   = (size_t)NTOT * 512;
constexpr size_t OFF_BALL  = OFF_WALL + SZ_WALL;
constexpr size_t OFF_STATS = OFF_BALL + NTOT * 4;
constexpr size_t OFF_SALL  = OFF_STATS + 2 * NTOT * 4;
constexpr size_t OFF_TALL  = OFF_SALL + NTOT * 4;
constexpr size_t OFF_QQ    = OFF_TALL + NTOT * 4;
constexpr size_t SZ_ONE    = (size_t)NPIX * 256 * 2;
constexpr size_t OFF_QK    = OFF_QQ + SZ_ONE;
constexpr size_t OFF_QV    = OFF_QK + SZ_ONE;
constexpr size_t WS_NEEDED = OFF_QV + SZ_ONE;

extern "C" void kernel_launch(void* const* d_in, const int* in_sizes, int n_in,
                              void* d_out, int out_size, void* d_ws, size_t ws_size,
                              hipStream_t stream) {
  (void)in_sizes; (void)n_in; (void)out_size;
  if (ws_size < WS_NEEDED) return;

  const float* x     = (const float*)d_in[0];
  const float* Wq    = (const float*)d_in[1];
  const float* bq    = (const float*)d_in[2];
  const float* Wk    = (const float*)d_in[3];
  const float* bk    = (const float*)d_in[4];
  const float* Wv    = (const float*)d_in[5];
  const float* bv    = (const float*)d_in[6];
  const float* gQ    = (const float*)d_in[7];
  const float* betaQ = (const float*)d_in[8];
  const float* gK    = (const float*)d_in[9];
  const float* betaK = (const float*)d_in[10];
  const float* gV    = (const float*)d_in[11];
  const float* betaV = (const float*)d_in[12];
  float* out = (float*)d_out;

  char* w = (char*)d_ws;
  u16*   xT    = (u16*)(w + OFF_XT);
  u16*   Wall  = (u16*)(w + OFF_WALL);
  float* ball  = (float*)(w + OFF_BALL);
  float* stats = (float*)(w + OFF_STATS);
  float* s_all = (float*)(w + OFF_SALL);
  float* t_all = (float*)(w + OFF_TALL);
  u16*   qQ    = (u16*)(w + OFF_QQ);
  u16*   qK    = (u16*)(w + OFF_QK);
  u16*   qV    = (u16*)(w + OFF_QV);

  k_prep<<<NTOT, 256, 0, stream>>>(Wq, bq, Wk, bk, Wv, bv, Wall, ball, stats);
  k_xt<<<NB, 384, 0, stream>>>(x, xT);
  k_gemm<<<dim3(6, NB), 512, 0, stream>>>(xT, Wall, ball, qQ, qK, qV, stats);
  k_stats<<<1, NTOT, 0, stream>>>(stats, gQ, betaQ, gK, betaK, gV, betaV, s_all, t_all);
  k_attn<<<dim3(NB, NHEADS), 384, 0, stream>>>(qQ, qK, qV, s_all, t_all, x, out);
}